// Round 8
// baseline (394.425 us; speedup 1.0000x reference)
//
#include <hip/hip_runtime.h>
#include <hip/hip_bf16.h>

// GCNII fused, bf16 pre-scaled activations (xs = dinv*x), src-only CSR built by
// two-pass bucket sort, degree-sorted node permutation. N=100000, E=1000000, F=64.
// Round-7 structure (one tile per block, best measured 297.3us) plus:
//  - software-pipelined gather: batch k+1 srcids+row loads issued before batch k
//    accumulate (byte-neutral, 2x in-flight rows for the typical 2-batch node);
//  - full-row coalesced y writes: MFMA results bounce through st, each 16-lane
//    group writes one contiguous 128B row (kills 4x32B partial-line RMW traffic
//    seen as WRITE_SIZE 12.5->37.5MB inflation).
// W/Wg MFMA A-fragments in registers; block-coop 16-node MFMA tile (bf16x3);
// last layer fuses the GCNConv GEMM. v_cvt_pk_bf16_f32 for all bf16 packs.
// Output: concat(out1 [N*4], out2 [N*3], h [N*64]) fp32.
// NOTE: record packing (dst&127)<<17 | src requires N <= 131072.

#define TPB 256
#define NBSH 7    // 128 nodes per bucket
typedef __hip_bfloat16 bf16;
typedef __attribute__((ext_vector_type(8))) short short8;  // 8 bf16 = 4 VGPR
typedef __attribute__((ext_vector_type(4))) float f32x4;   // MFMA C/D frag

#define MFMA16(A, B, C) __builtin_amdgcn_mfma_f32_16x16x32_bf16((A), (B), (C), 0, 0, 0)

__device__ __forceinline__ float lo16(int u) { return __int_as_float(u << 16); }
__device__ __forceinline__ float hi16(int u) { return __int_as_float(u & 0xffff0000); }

// packed f32x2 -> bf16x2 (RNE), lo in [15:0], hi in [31:16]
__device__ __forceinline__ unsigned cvtpk(float lo, float hi) {
    unsigned r;
    asm("v_cvt_pk_bf16_f32 %0, %1, %2" : "=v"(r) : "v"(lo), "v"(hi));
    return r;
}

// ---- pass 0: bucket histogram (LDS-privatized) ----
__global__ void ebhist_kernel(const int* __restrict__ col, int* __restrict__ bh,
                              int E, int B) {
    __shared__ int lh[800];
    for (int i = threadIdx.x; i < B; i += blockDim.x) lh[i] = 0;
    __syncthreads();
    for (int e = blockIdx.x * blockDim.x + threadIdx.x; e < E; e += gridDim.x * blockDim.x)
        atomicAdd(&lh[col[e] >> NBSH], 1);
    __syncthreads();
    for (int i = threadIdx.x; i < B; i += blockDim.x) {
        int c = lh[i];
        if (c) atomicAdd(&bh[i], c);
    }
}

// ---- exclusive scan of bh -> bcur (cursors) and boff (bounds, boff[B]=E) ----
__global__ void bscan_kernel(const int* __restrict__ bh, int* __restrict__ bcur,
                             int* __restrict__ boff, int B, int E) {
    __shared__ int s[256];
    int t = threadIdx.x;
    int v[4]; int sum = 0;
#pragma unroll
    for (int i = 0; i < 4; ++i) {
        int idx = t * 4 + i;
        v[i] = (idx < B) ? bh[idx] : 0;
        sum += v[i];
    }
    s[t] = sum;
    __syncthreads();
    for (int off = 1; off < 256; off <<= 1) {
        int val = (t >= off) ? s[t - off] : 0;
        __syncthreads();
        s[t] += val;
        __syncthreads();
    }
    int run = s[t] - sum;
#pragma unroll
    for (int i = 0; i < 4; ++i) {
        int idx = t * 4 + i;
        if (idx < B) { bcur[idx] = run; boff[idx] = run; }
        run += v[i];
    }
    if (t == 255) boff[B] = E;
}

// ---- pass 1: bucket scatter with per-block range reservation ----
__global__ void bucket_scatter_kernel(const int* __restrict__ ei, int* __restrict__ bcur,
                                      unsigned int* __restrict__ ebuf, int E, int B) {
    __shared__ int lh[800], lb[800];
    int chunk = (E + gridDim.x - 1) / gridDim.x;
    int beg = blockIdx.x * chunk;
    int end = min(beg + chunk, E);
    for (int i = threadIdx.x; i < B; i += blockDim.x) lh[i] = 0;
    __syncthreads();
    for (int e = beg + threadIdx.x; e < end; e += blockDim.x)
        atomicAdd(&lh[ei[E + e] >> NBSH], 1);
    __syncthreads();
    for (int i = threadIdx.x; i < B; i += blockDim.x) {
        int c = lh[i];
        lb[i] = c ? atomicAdd(&bcur[i], c) : 0;   // one global atomic per bin per block
    }
    __syncthreads();
    for (int i = threadIdx.x; i < B; i += blockDim.x) lh[i] = 0;
    __syncthreads();
    for (int e = beg + threadIdx.x; e < end; e += blockDim.x) {
        int r = ei[e];
        int c = ei[E + e];
        int bin = c >> NBSH;
        int rank = atomicAdd(&lh[bin], 1);        // LDS rank
        ebuf[lb[bin] + rank] = ((unsigned)(c & 127) << 17) | (unsigned)r;
    }
}

// ---- pass 2: per-bucket place; also emits degi/rowptr/dinv/sdeg ----
__global__ __launch_bounds__(128) void bucket_place_kernel(
        const int* __restrict__ boff, const unsigned int* __restrict__ ebuf,
        int* __restrict__ rowptr, int* __restrict__ degi,
        float* __restrict__ dinv, float* __restrict__ sdeg,
        int* __restrict__ srcids, int n) {
    __shared__ int cnt[128], loff[128], lcur[128];
    int b = blockIdx.x;
    int t = threadIdx.x;
    int lo = boff[b];
    int hi = boff[b + 1];
    int vbase = b << NBSH;
    cnt[t] = 0;
    __syncthreads();
    for (int i = lo + t; i < hi; i += 128)
        atomicAdd(&cnt[ebuf[i] >> 17], 1);
    __syncthreads();
    int mine = cnt[t];
    loff[t] = mine;
    __syncthreads();
    for (int off = 1; off < 128; off <<= 1) {
        int val = (t >= off) ? loff[t - off] : 0;
        __syncthreads();
        loff[t] += val;
        __syncthreads();
    }
    int excl = loff[t] - mine;
    int v = vbase + t;
    if (v < n) {
        rowptr[v] = lo + excl;
        degi[v] = mine;
        float d = (float)mine + 1.0f;
        dinv[v] = rsqrtf(d);
        sdeg[v] = sqrtf(d);
    }
    lcur[t] = lo + excl;
    __syncthreads();
    for (int i = lo + t; i < hi; i += 128) {
        unsigned int r = ebuf[i];
        int pos = atomicAdd(&lcur[r >> 17], 1);
        srcids[pos] = (int)(r & 0x1FFFFu);
    }
}

// ---- degree histogram (LDS-privatized) ----
__global__ void dhist_kernel(const int* __restrict__ degi, int* __restrict__ dh, int n) {
    __shared__ int lh[256];
    lh[threadIdx.x] = 0;
    __syncthreads();
    for (int v = blockIdx.x * blockDim.x + threadIdx.x; v < n; v += gridDim.x * blockDim.x)
        atomicAdd(&lh[min(degi[v], 255)], 1);
    __syncthreads();
    int c = lh[threadIdx.x];
    if (c) atomicAdd(&dh[threadIdx.x], c);
}

__global__ void dscan_kernel(const int* __restrict__ dh, int* __restrict__ dcur) {
    __shared__ int s[256];
    int t = threadIdx.x;
    int mine = dh[t];
    s[t] = mine;
    __syncthreads();
    for (int off = 1; off < 256; off <<= 1) {
        int val = (t >= off) ? s[t - off] : 0;
        __syncthreads();
        s[t] += val;
        __syncthreads();
    }
    dcur[t] = s[t] - mine;  // exclusive
}

// ---- placement: per-block chunk, LDS hist -> bulk range reservation -> LDS rank ----
__global__ void place_kernel(const int* __restrict__ degi, int* __restrict__ dcur,
                             int* __restrict__ perm, int n) {
    __shared__ int lh[256], lb[256];
    int chunk = (n + gridDim.x - 1) / gridDim.x;
    int beg = blockIdx.x * chunk;
    int end = min(beg + chunk, n);
    lh[threadIdx.x] = 0;
    __syncthreads();
    for (int v = beg + threadIdx.x; v < end; v += blockDim.x)
        atomicAdd(&lh[min(degi[v], 255)], 1);
    __syncthreads();
    int c = lh[threadIdx.x];
    lb[threadIdx.x] = c ? atomicAdd(&dcur[threadIdx.x], c) : 0;
    __syncthreads();
    lh[threadIdx.x] = 0;
    __syncthreads();
    for (int v = beg + threadIdx.x; v < end; v += blockDim.x) {
        int bin = min(degi[v], 255);
        int r = atomicAdd(&lh[bin], 1);
        perm[lb[bin] + r] = v;
    }
}

// ---- x0s = bf16(dinv[v] * x) ----
__global__ void cvt_kernel(const float* __restrict__ x, const float* __restrict__ dinv,
                           unsigned short* __restrict__ xb, int n4) {
    int i = blockIdx.x * blockDim.x + threadIdx.x;
    if (i < n4) {
        float dv = dinv[i >> 4];
        float4 f = ((const float4*)x)[i];
        uint2 o;
        o.x = cvtpk(f.x * dv, f.y * dv);
        o.y = cvtpk(f.z * dv, f.w * dv);
        ((uint2*)xb)[i] = o;
    }
}

// ---- per-wave W A-fragments (W^T is the A operand) in REGISTERS, bf16 hi+lo.
// Lane l of wave wid holds A[m = l&15][k = (l>>4)*8 + j], j=0..7 for k-steps
// kk=0,1 -> W[kk*32 + (l>>4)*8 + j][wid*16 + (l&15)].
struct WFrag { short8 h0, l0, h1, l1; };
__device__ __forceinline__ WFrag load_wfrag(const float* __restrict__ W, int col, int kg) {
    union { short8 v; unsigned u[4]; } H0, L0, H1, L1;
#pragma unroll
    for (int j = 0; j < 4; ++j) {
        float w0 = W[(kg * 8 + 2 * j) * 64 + col];
        float w1 = W[(kg * 8 + 2 * j + 1) * 64 + col];
        unsigned h = cvtpk(w0, w1);
        float h0 = __uint_as_float(h << 16);
        float h1 = __uint_as_float(h & 0xffff0000u);
        H0.u[j] = h;
        L0.u[j] = cvtpk(w0 - h0, w1 - h1);
        float v0 = W[(32 + kg * 8 + 2 * j) * 64 + col];
        float v1 = W[(32 + kg * 8 + 2 * j + 1) * 64 + col];
        unsigned g = cvtpk(v0, v1);
        float g0 = __uint_as_float(g << 16);
        float g1 = __uint_as_float(g & 0xffff0000u);
        H1.u[j] = g;
        L1.u[j] = cvtpk(v0 - g0, v1 - g1);
    }
    WFrag r;
    r.h0 = H0.v; r.l0 = L0.v; r.h1 = H1.v; r.l1 = L1.v;
    return r;
}

// ---- build the B operand (t^T) fragment from an st row: 8 consecutive fp32,
// split into bf16 hi (RNE) + lo (RNE of exact residual) via v_cvt_pk_bf16_f32.
__device__ __forceinline__ void build_bfrag(const float* __restrict__ tp,
                                            short8* bh, short8* bl) {
    float4 ta = *(const float4*)tp;
    float4 tb = *(const float4*)(tp + 4);
    float tv[8] = {ta.x, ta.y, ta.z, ta.w, tb.x, tb.y, tb.z, tb.w};
    union { short8 v; unsigned u[4]; } H, L;
#pragma unroll
    for (int j = 0; j < 4; ++j) {
        unsigned h = cvtpk(tv[2 * j], tv[2 * j + 1]);
        float h0 = __uint_as_float(h << 16);
        float h1 = __uint_as_float(h & 0xffff0000u);
        H.u[j] = h;
        L.u[j] = cvtpk(tv[2 * j] - h0, tv[2 * j + 1] - h1);
    }
    *bh = H.v;
    *bl = L.v;
}

// 6-MFMA bf16x3 tile: hi*hi + lo*hi + hi*lo over 2 k-steps
__device__ __forceinline__ f32x4 mm6(const WFrag& w, short8 bh0, short8 bl0,
                                     short8 bh1, short8 bl1) {
    f32x4 ac = {0.f, 0.f, 0.f, 0.f};
    ac = MFMA16(w.h0, bh0, ac);
    ac = MFMA16(w.l0, bh0, ac);
    ac = MFMA16(w.h0, bl0, ac);
    ac = MFMA16(w.h1, bh1, ac);
    ac = MFMA16(w.l1, bh1, ac);
    ac = MFMA16(w.h1, bl1, ac);
    return ac;
}

// ---- 4-slot gather, software-pipelined 8-edge batches: batch k+1's srcid+row
// loads are issued BEFORE batch k's accumulate -> 16 rows in flight in steady
// state, 8 for single-batch rows (byte-neutral vs round 7). md is wave-uniform
// (max over the 4 slots). Over-reads land in later CSR rows or the zeroed pad
// and are masked out of the accumulation.
struct GRes { float a0, a1, a2, a3; };
__device__ __forceinline__ GRes gather8p(const int* __restrict__ srcids, int beg, int deg,
                                         int md, const unsigned short* __restrict__ xsb,
                                         int ge) {
    GRes r{0.0f, 0.0f, 0.0f, 0.0f};
    int2 q[8];
    {
        int src[8];
#pragma unroll
        for (int u = 0; u < 8; ++u)
            src[u] = srcids[beg + u];
#pragma unroll
        for (int u = 0; u < 8; ++u)
            q[u] = *(const int2*)(xsb + ((unsigned)src[u] * 64u + (unsigned)ge));
    }
    int i = 0;
    for (; i + 8 < md; i += 8) {
        int2 q2[8];
        {
            int src[8];
#pragma unroll
            for (int u = 0; u < 8; ++u)
                src[u] = srcids[beg + i + 8 + u];
#pragma unroll
            for (int u = 0; u < 8; ++u)
                q2[u] = *(const int2*)(xsb + ((unsigned)src[u] * 64u + (unsigned)ge));
        }
#pragma unroll
        for (int u = 0; u < 8; ++u) {
            float m = (i + u < deg) ? 1.0f : 0.0f;
            r.a0 = fmaf(m, lo16(q[u].x), r.a0);
            r.a1 = fmaf(m, hi16(q[u].x), r.a1);
            r.a2 = fmaf(m, lo16(q[u].y), r.a2);
            r.a3 = fmaf(m, hi16(q[u].y), r.a3);
        }
#pragma unroll
        for (int u = 0; u < 8; ++u) q[u] = q2[u];
    }
#pragma unroll
    for (int u = 0; u < 8; ++u) {
        float m = (i + u < deg) ? 1.0f : 0.0f;
        r.a0 = fmaf(m, lo16(q[u].x), r.a0);
        r.a1 = fmaf(m, hi16(q[u].x), r.a1);
        r.a2 = fmaf(m, lo16(q[u].y), r.a2);
        r.a3 = fmaf(m, hi16(q[u].y), r.a3);
    }
    return r;
}

// ---- fused GCN2Conv layer: ys_out = dinv * relu( t @ W ),
//      t = 0.9*dinv*(S + xs_self) + 0.1*sdeg*xs_self; block-coop MFMA (bf16x3).
// One tile per block. Epilogue bounces results through st so each 16-lane group
// writes one full 128B row contiguously (no partial-line RMW).
__global__ __launch_bounds__(256, 7) void layer_kernel(
        const int* __restrict__ rowptr, const int* __restrict__ degi,
        const int* __restrict__ srcids, const int* __restrict__ perm,
        const unsigned short* __restrict__ xsb, const float* __restrict__ dinv,
        const float* __restrict__ sdeg, const float* __restrict__ W,
        unsigned short* __restrict__ yb, int n) {
    __shared__ __align__(16) float st[16][68];             // 16 nodes x 64 feat (+4 pad)
    int wid = threadIdx.x >> 6;
    int lane = threadIdx.x & 63;
    int s = lane >> 4;    // gather: node slot   | matmul: k-group
    int g = lane & 15;    // gather: feature quad| matmul: node (B col / D col)
    WFrag wA = load_wfrag(W, wid * 16 + g, s);             // registers, once
    int ntile = (n + 15) >> 4;
    int tile = ntile - 1 - blockIdx.x;
    int base = tile * 16;
    int vb = base + wid * 4 + s;
    int vbc = (vb < n) ? vb : n - 1;
    int v = perm[vbc];
    int beg = rowptr[v];
    int deg = degi[v];
    int md = max(deg, __shfl_xor(deg, 16));
    md = max(md, __shfl_xor(md, 32));
    GRes r = gather8p(srcids, beg, deg, md, xsb, g * 4);
    int2 qs = *(const int2*)(xsb + ((unsigned)v * 64u + (unsigned)(g * 4)));
    float xs0 = lo16(qs.x), xs1 = hi16(qs.x), xs2 = lo16(qs.y), xs3 = hi16(qs.y);
    float c9 = 0.9f * dinv[v];
    float c1 = 0.1f * sdeg[v];
    float4 t4;
    t4.x = c9 * (r.a0 + xs0) + c1 * xs0;
    t4.y = c9 * (r.a1 + xs1) + c1 * xs1;
    t4.z = c9 * (r.a2 + xs2) + c1 * xs2;
    t4.w = c9 * (r.a3 + xs3) + c1 * xs3;
    *(float4*)&st[wid * 4 + s][g * 4] = t4;
    __syncthreads();                                   // (A) st tile complete
    // ---- MFMA: D[outf = wid*16 + s*4 + j][node = g] ----
    int vb2 = base + g;
    int v2c = perm[(vb2 < n) ? vb2 : n - 1];
    float dv2 = dinv[v2c];
    const float* strow = st[g];
    short8 bh0, bl0, bh1, bl1;
    build_bfrag(strow + s * 8,      &bh0, &bl0);
    build_bfrag(strow + 32 + s * 8, &bh1, &bl1);
    __syncthreads();                                   // (B) st reads done
    f32x4 ac = mm6(wA, bh0, bl0, bh1, bl1);
    *(float4*)&st[g][wid * 16 + s * 4] = make_float4(
        fmaxf(ac[0], 0.f) * dv2, fmaxf(ac[1], 0.f) * dv2,
        fmaxf(ac[2], 0.f) * dv2, fmaxf(ac[3], 0.f) * dv2);
    __syncthreads();                                   // (C) results staged in st
    // coalesced full-row write: 16 lanes x 8B = 128B contiguous per node row
    int rowi = threadIdx.x >> 4;
    int quad = threadIdx.x & 15;
    int vbw = base + rowi;
    if (vbw < n) {
        int vw = perm[vbw];
        float4 y4 = *(const float4*)&st[rowi][quad * 4];
        uint2 o;
        o.x = cvtpk(y4.x, y4.y);
        o.y = cvtpk(y4.z, y4.w);
        *(uint2*)(yb + ((size_t)(unsigned)vw << 6) + (unsigned)(quad * 4)) = o;
    }
}

// ---- last GCN2Conv layer fused with GCNConv GEMM: xw = (dinv*relu(t@W)) @ Wg ----
__global__ __launch_bounds__(256, 6) void layer_fused_kernel(
        const int* __restrict__ rowptr, const int* __restrict__ degi,
        const int* __restrict__ srcids, const int* __restrict__ perm,
        const unsigned short* __restrict__ xsb, const float* __restrict__ dinv,
        const float* __restrict__ sdeg, const float* __restrict__ W,
        const float* __restrict__ Wg, unsigned short* __restrict__ yb, int n) {
    __shared__ __align__(16) float st[16][68];
    int wid = threadIdx.x >> 6;
    int lane = threadIdx.x & 63;
    int s = lane >> 4;
    int g = lane & 15;
    WFrag wA = load_wfrag(W,  wid * 16 + g, s);
    WFrag wG = load_wfrag(Wg, wid * 16 + g, s);
    int ntile = (n + 15) >> 4;
    int tile = ntile - 1 - blockIdx.x;
    int base = tile * 16;
    int vb = base + wid * 4 + s;
    int vbc = (vb < n) ? vb : n - 1;
    int v = perm[vbc];
    int beg = rowptr[v];
    int deg = degi[v];
    int md = max(deg, __shfl_xor(deg, 16));
    md = max(md, __shfl_xor(md, 32));
    GRes r = gather8p(srcids, beg, deg, md, xsb, g * 4);
    int2 qs = *(const int2*)(xsb + ((unsigned)v * 64u + (unsigned)(g * 4)));
    float xs0 = lo16(qs.x), xs1 = hi16(qs.x), xs2 = lo16(qs.y), xs3 = hi16(qs.y);
    float c9 = 0.9f * dinv[v];
    float c1 = 0.1f * sdeg[v];
    float4 t4;
    t4.x = c9 * (r.a0 + xs0) + c1 * xs0;
    t4.y = c9 * (r.a1 + xs1) + c1 * xs1;
    t4.z = c9 * (r.a2 + xs2) + c1 * xs2;
    t4.w = c9 * (r.a3 + xs3) + c1 * xs3;
    *(float4*)&st[wid * 4 + s][g * 4] = t4;
    __syncthreads();                                   // (A) st tile complete
    int vb2 = base + g;
    int v2c = perm[(vb2 < n) ? vb2 : n - 1];
    float dv2 = dinv[v2c];
    const float* strow = st[g];
    // ---- matmul 1: y3s = dinv * relu(t @ W), written back to st (fp32) ----
    {
        short8 bh0, bl0, bh1, bl1;
        build_bfrag(strow + s * 8,      &bh0, &bl0);
        build_bfrag(strow + 32 + s * 8, &bh1, &bl1);
        __syncthreads();                               // (B) all B1 reads done
        f32x4 ac = mm6(wA, bh0, bl0, bh1, bl1);
        *(float4*)&st[g][wid * 16 + s * 4] = make_float4(
            fmaxf(ac[0], 0.f) * dv2, fmaxf(ac[1], 0.f) * dv2,
            fmaxf(ac[2], 0.f) * dv2, fmaxf(ac[3], 0.f) * dv2);
    }
    __syncthreads();                                   // (C) y3s writeback complete
    // ---- matmul 2: xw = y3s @ Wg (no relu, no extra scale) ----
    {
        short8 bh0, bl0, bh1, bl1;
        build_bfrag(strow + s * 8,      &bh0, &bl0);
        build_bfrag(strow + 32 + s * 8, &bh1, &bl1);
        __syncthreads();                               // (D) B2 reads done
        f32x4 ac = mm6(wG, bh0, bl0, bh1, bl1);
        *(float4*)&st[g][wid * 16 + s * 4] = make_float4(ac[0], ac[1], ac[2], ac[3]);
    }
    __syncthreads();                                   // (E) xw staged in st
    // coalesced full-row write
    int rowi = threadIdx.x >> 4;
    int quad = threadIdx.x & 15;
    int vbw = base + rowi;
    if (vbw < n) {
        int vw = perm[vbw];
        float4 y4 = *(const float4*)&st[rowi][quad * 4];
        uint2 o;
        o.x = cvtpk(y4.x, y4.y);
        o.y = cvtpk(y4.z, y4.w);
        *(uint2*)(yb + ((size_t)(unsigned)vw << 6) + (unsigned)(quad * 4)) = o;
    }
}

// ---- final: h = dinv*(S + xws_self) + b_gcn; out1 = h@W1+b1; out2 = h@W2+b2 ----
__global__ __launch_bounds__(256, 7) void heads_kernel(
        const int* __restrict__ rowptr, const int* __restrict__ degi,
        const int* __restrict__ srcids, const int* __restrict__ perm,
        const unsigned short* __restrict__ xwb, const float* __restrict__ dinv,
        const float* __restrict__ bg,
        const float* __restrict__ W1, const float* __restrict__ b1,
        const float* __restrict__ W2, const float* __restrict__ b2,
        float* __restrict__ out, int n) {
    __shared__ __align__(16) float hs[4][4][64];
    __shared__ __align__(16) float whd[448];   // whd[j*64+k], j=0..6
    __shared__ float bs[8];
    int wid = threadIdx.x >> 6;
    int lane = threadIdx.x & 63;
    int s = lane >> 4;
    int g = lane & 15;
    for (int i = threadIdx.x; i < 448; i += TPB) {   // blockDim 256 < 448: loop!
        int j = i >> 6, k = i & 63;
        whd[i] = (j < 4) ? W1[k * 4 + j] : W2[k * 3 + (j - 4)];
    }
    if (threadIdx.x < 7) bs[threadIdx.x] = (threadIdx.x < 4) ? b1[threadIdx.x] : b2[threadIdx.x - 4];
    __syncthreads();
    int j = lane >> 3;
    int k0 = (lane & 7) * 8;
    int ntile = (n + 15) >> 4;
    int tile = ntile - 1 - blockIdx.x;
    int base = tile * 16 + wid * 4;
    int vb = base + s;
    int vbc = (vb < n) ? vb : n - 1;
    int v = perm[vbc];
    int beg = rowptr[v];
    int deg = degi[v];
    int md = max(deg, __shfl_xor(deg, 16));
    md = max(md, __shfl_xor(md, 32));
    GRes r = gather8p(srcids, beg, deg, md, xwb, g * 4);
    int2 qs = *(const int2*)(xwb + ((unsigned)v * 64u + (unsigned)(g * 4)));
    float dv = dinv[v];
    float4 bq = *(const float4*)(bg + g * 4);
    float4 h4;
    h4.x = dv * (r.a0 + lo16(qs.x)) + bq.x;
    h4.y = dv * (r.a1 + hi16(qs.x)) + bq.y;
    h4.z = dv * (r.a2 + lo16(qs.y)) + bq.z;
    h4.w = dv * (r.a3 + hi16(qs.y)) + bq.w;
    if (vb < n)
        *(float4*)&out[(size_t)7 * n + (size_t)(unsigned)v * 64 + g * 4] = h4;
    *(float4*)&hs[wid][s][g * 4] = h4;
    __builtin_amdgcn_wave_barrier();
#pragma unroll
    for (int ss = 0; ss < 4; ++ss) {
        int vb2 = base + ss;
        if (vb2 >= n) break;
        int v2 = perm[vb2];
        float part = 0.0f;
        if (j < 7) {
            float4 h0 = *(const float4*)&hs[wid][ss][k0];
            float4 h1 = *(const float4*)&hs[wid][ss][k0 + 4];
            const float4* wq = (const float4*)&whd[j * 64 + k0];
            float4 w0 = wq[0], w1 = wq[1];
            part = h0.x * w0.x + h0.y * w0.y + h0.z * w0.z + h0.w * w0.w
                 + h1.x * w1.x + h1.y * w1.y + h1.z * w1.z + h1.w * w1.w;
        }
        part += __shfl_down(part, 4);
        part += __shfl_down(part, 2);
        part += __shfl_down(part, 1);
        if ((lane & 7) == 0 && j < 7) {
            float sv = bs[j] + part;
            if (j < 4) out[(size_t)v2 * 4 + j] = sv;
            else       out[(size_t)4 * n + (size_t)v2 * 3 + (j - 4)] = sv;
        }
    }
}

extern "C" void kernel_launch(void* const* d_in, const int* in_sizes, int n_in,
                              void* d_out, int out_size, void* d_ws, size_t ws_size,
                              hipStream_t stream) {
    const float* x     = (const float*)d_in[0];
    const int*   ei    = (const int*)d_in[1];
    const float* Ws    = (const float*)d_in[2];
    const float* W_gcn = (const float*)d_in[3];
    const float* b_gcn = (const float*)d_in[4];
    const float* W1    = (const float*)d_in[5];
    const float* b1    = (const float*)d_in[6];
    const float* W2    = (const float*)d_in[7];
    const float* b2    = (const float*)d_in[8];
    float* out = (float*)d_out;

    const int N = in_sizes[0] / 64;
    const int E = in_sizes[1] / 2;
    const int NLAYERS = in_sizes[2] / 4096;  // L-1 = 3
    const int B = (N + 127) >> NBSH;         // node buckets of 128
    const int NTILE = (N + 15) >> 4;         // one block per 16-node tile

    // ws layout (ints): degi[N] rowptr[N] bh[800] bcur[800] boff[800]
    //                   dh[256] dcur[256] perm[N] srcids[E+64] ebuf[E]
    // (floats): dinv[N] sdeg[N] | (ushort): x0s, bufA, bufB (N*64 each)
    int*   degi   = (int*)d_ws;
    int*   rowptr = degi + N;
    int*   bh     = rowptr + N;
    int*   bcur   = bh + 800;
    int*   boff   = bcur + 800;
    int*   dh     = boff + 800;
    int*   dcur   = dh + 256;
    int*   perm   = dcur + 256;
    int*   srcids = perm + N;
    unsigned int* ebuf = (unsigned int*)(srcids + E + 64);
    float* dinv   = (float*)(ebuf + E);
    float* sdeg   = dinv + N;
    unsigned short* x0s  = (unsigned short*)(sdeg + N);
    unsigned short* bufA = x0s + (size_t)N * 64;
    unsigned short* bufB = bufA + (size_t)N * 64;

    // ---- CSR build: two-pass bucket sort ----
    hipMemsetAsync(bh, 0, 800 * sizeof(int), stream);
    hipMemsetAsync(dh, 0, 256 * sizeof(int), stream);
    hipMemsetAsync(srcids + E, 0, 64 * sizeof(int), stream);  // gather tail pad
    ebhist_kernel<<<120, TPB, 0, stream>>>(ei + E, bh, E, B);
    bscan_kernel<<<1, 256, 0, stream>>>(bh, bcur, boff, B, E);
    bucket_scatter_kernel<<<120, TPB, 0, stream>>>(ei, bcur, ebuf, E, B);
    bucket_place_kernel<<<B, 128, 0, stream>>>(boff, ebuf, rowptr, degi, dinv, sdeg,
                                               srcids, N);
    // ---- degree-sorted permutation ----
    dhist_kernel<<<64, 256, 0, stream>>>(degi, dh, N);
    dscan_kernel<<<1, 256, 0, stream>>>(dh, dcur);
    place_kernel<<<64, 256, 0, stream>>>(degi, dcur, perm, N);
    cvt_kernel<<<(N * 16 + TPB - 1) / TPB, TPB, 0, stream>>>(x, dinv, x0s, N * 16);

    // ---- GCN2Conv layers: first NLAYERS-1 plain, last fused with GCNConv GEMM ----
    const unsigned short* xcur = x0s;
    unsigned short* ybuf = bufA;
    for (int i = 0; i < NLAYERS - 1; ++i) {
        layer_kernel<<<NTILE, TPB, 0, stream>>>(rowptr, degi, srcids, perm, xcur,
                                                dinv, sdeg, Ws + (size_t)i * 4096, ybuf, N);
        xcur = ybuf;
        ybuf = (ybuf == bufA) ? bufB : bufA;
    }
    layer_fused_kernel<<<NTILE, TPB, 0, stream>>>(rowptr, degi, srcids, perm, xcur,
                                                  dinv, sdeg,
                                                  Ws + (size_t)(NLAYERS - 1) * 4096,
                                                  W_gcn, ybuf, N);
    unsigned short* xw = ybuf;

    // ---- heads ----
    heads_kernel<<<NTILE, TPB, 0, stream>>>(rowptr, degi, srcids, perm, xw, dinv,
                                            b_gcn, W1, b1, W2, b2, out, N);
}

// Round 9
// 295.233 us; speedup vs baseline: 1.3360x; 1.3360x over previous
//
#include <hip/hip_runtime.h>
#include <hip/hip_bf16.h>

// GCNII fused, bf16 pre-scaled activations (xs = dinv*x), src-only CSR built by
// two-pass bucket sort, degree-sorted node permutation. N=100000, E=1000000, F=64.
// Round-7 structure (one tile per block, best measured 297.3us) + full-row
// coalesced y writes ONLY: MFMA results bounce through st, each 16-lane group
// writes one contiguous 128B row (kills 4x32B partial-line RMW, WRITE_SIZE
// 37.5MB -> ~13MB). Round-8's software-pipelined gather is REVERTED: it pushed
// register liveness past the launch_bounds cap and spilled to scratch
// (FETCH+WRITE both +100MB, 76us/dispatch).
// 8-deep gather; W/Wg MFMA A-fragments in registers; block-coop 16-node MFMA
// tile (bf16x3); last layer fuses the GCNConv GEMM.
// Output: concat(out1 [N*4], out2 [N*3], h [N*64]) fp32.
// NOTE: record packing (dst&127)<<17 | src requires N <= 131072.

#define TPB 256
#define NBSH 7    // 128 nodes per bucket
typedef __hip_bfloat16 bf16;
typedef __attribute__((ext_vector_type(8))) short short8;  // 8 bf16 = 4 VGPR
typedef __attribute__((ext_vector_type(4))) float f32x4;   // MFMA C/D frag

#define MFMA16(A, B, C) __builtin_amdgcn_mfma_f32_16x16x32_bf16((A), (B), (C), 0, 0, 0)

__device__ __forceinline__ float lo16(int u) { return __int_as_float(u << 16); }
__device__ __forceinline__ float hi16(int u) { return __int_as_float(u & 0xffff0000); }

// packed f32x2 -> bf16x2 (RNE), lo in [15:0], hi in [31:16]
__device__ __forceinline__ unsigned cvtpk(float lo, float hi) {
    unsigned r;
    asm("v_cvt_pk_bf16_f32 %0, %1, %2" : "=v"(r) : "v"(lo), "v"(hi));
    return r;
}

// ---- pass 0: bucket histogram (LDS-privatized) ----
__global__ void ebhist_kernel(const int* __restrict__ col, int* __restrict__ bh,
                              int E, int B) {
    __shared__ int lh[800];
    for (int i = threadIdx.x; i < B; i += blockDim.x) lh[i] = 0;
    __syncthreads();
    for (int e = blockIdx.x * blockDim.x + threadIdx.x; e < E; e += gridDim.x * blockDim.x)
        atomicAdd(&lh[col[e] >> NBSH], 1);
    __syncthreads();
    for (int i = threadIdx.x; i < B; i += blockDim.x) {
        int c = lh[i];
        if (c) atomicAdd(&bh[i], c);
    }
}

// ---- exclusive scan of bh -> bcur (cursors) and boff (bounds, boff[B]=E) ----
__global__ void bscan_kernel(const int* __restrict__ bh, int* __restrict__ bcur,
                             int* __restrict__ boff, int B, int E) {
    __shared__ int s[256];
    int t = threadIdx.x;
    int v[4]; int sum = 0;
#pragma unroll
    for (int i = 0; i < 4; ++i) {
        int idx = t * 4 + i;
        v[i] = (idx < B) ? bh[idx] : 0;
        sum += v[i];
    }
    s[t] = sum;
    __syncthreads();
    for (int off = 1; off < 256; off <<= 1) {
        int val = (t >= off) ? s[t - off] : 0;
        __syncthreads();
        s[t] += val;
        __syncthreads();
    }
    int run = s[t] - sum;
#pragma unroll
    for (int i = 0; i < 4; ++i) {
        int idx = t * 4 + i;
        if (idx < B) { bcur[idx] = run; boff[idx] = run; }
        run += v[i];
    }
    if (t == 255) boff[B] = E;
}

// ---- pass 1: bucket scatter with per-block range reservation ----
__global__ void bucket_scatter_kernel(const int* __restrict__ ei, int* __restrict__ bcur,
                                      unsigned int* __restrict__ ebuf, int E, int B) {
    __shared__ int lh[800], lb[800];
    int chunk = (E + gridDim.x - 1) / gridDim.x;
    int beg = blockIdx.x * chunk;
    int end = min(beg + chunk, E);
    for (int i = threadIdx.x; i < B; i += blockDim.x) lh[i] = 0;
    __syncthreads();
    for (int e = beg + threadIdx.x; e < end; e += blockDim.x)
        atomicAdd(&lh[ei[E + e] >> NBSH], 1);
    __syncthreads();
    for (int i = threadIdx.x; i < B; i += blockDim.x) {
        int c = lh[i];
        lb[i] = c ? atomicAdd(&bcur[i], c) : 0;   // one global atomic per bin per block
    }
    __syncthreads();
    for (int i = threadIdx.x; i < B; i += blockDim.x) lh[i] = 0;
    __syncthreads();
    for (int e = beg + threadIdx.x; e < end; e += blockDim.x) {
        int r = ei[e];
        int c = ei[E + e];
        int bin = c >> NBSH;
        int rank = atomicAdd(&lh[bin], 1);        // LDS rank
        ebuf[lb[bin] + rank] = ((unsigned)(c & 127) << 17) | (unsigned)r;
    }
}

// ---- pass 2: per-bucket place; also emits degi/rowptr/dinv/sdeg ----
__global__ __launch_bounds__(128) void bucket_place_kernel(
        const int* __restrict__ boff, const unsigned int* __restrict__ ebuf,
        int* __restrict__ rowptr, int* __restrict__ degi,
        float* __restrict__ dinv, float* __restrict__ sdeg,
        int* __restrict__ srcids, int n) {
    __shared__ int cnt[128], loff[128], lcur[128];
    int b = blockIdx.x;
    int t = threadIdx.x;
    int lo = boff[b];
    int hi = boff[b + 1];
    int vbase = b << NBSH;
    cnt[t] = 0;
    __syncthreads();
    for (int i = lo + t; i < hi; i += 128)
        atomicAdd(&cnt[ebuf[i] >> 17], 1);
    __syncthreads();
    int mine = cnt[t];
    loff[t] = mine;
    __syncthreads();
    for (int off = 1; off < 128; off <<= 1) {
        int val = (t >= off) ? loff[t - off] : 0;
        __syncthreads();
        loff[t] += val;
        __syncthreads();
    }
    int excl = loff[t] - mine;
    int v = vbase + t;
    if (v < n) {
        rowptr[v] = lo + excl;
        degi[v] = mine;
        float d = (float)mine + 1.0f;
        dinv[v] = rsqrtf(d);
        sdeg[v] = sqrtf(d);
    }
    lcur[t] = lo + excl;
    __syncthreads();
    for (int i = lo + t; i < hi; i += 128) {
        unsigned int r = ebuf[i];
        int pos = atomicAdd(&lcur[r >> 17], 1);
        srcids[pos] = (int)(r & 0x1FFFFu);
    }
}

// ---- degree histogram (LDS-privatized) ----
__global__ void dhist_kernel(const int* __restrict__ degi, int* __restrict__ dh, int n) {
    __shared__ int lh[256];
    lh[threadIdx.x] = 0;
    __syncthreads();
    for (int v = blockIdx.x * blockDim.x + threadIdx.x; v < n; v += gridDim.x * blockDim.x)
        atomicAdd(&lh[min(degi[v], 255)], 1);
    __syncthreads();
    int c = lh[threadIdx.x];
    if (c) atomicAdd(&dh[threadIdx.x], c);
}

__global__ void dscan_kernel(const int* __restrict__ dh, int* __restrict__ dcur) {
    __shared__ int s[256];
    int t = threadIdx.x;
    int mine = dh[t];
    s[t] = mine;
    __syncthreads();
    for (int off = 1; off < 256; off <<= 1) {
        int val = (t >= off) ? s[t - off] : 0;
        __syncthreads();
        s[t] += val;
        __syncthreads();
    }
    dcur[t] = s[t] - mine;  // exclusive
}

// ---- placement: per-block chunk, LDS hist -> bulk range reservation -> LDS rank ----
__global__ void place_kernel(const int* __restrict__ degi, int* __restrict__ dcur,
                             int* __restrict__ perm, int n) {
    __shared__ int lh[256], lb[256];
    int chunk = (n + gridDim.x - 1) / gridDim.x;
    int beg = blockIdx.x * chunk;
    int end = min(beg + chunk, n);
    lh[threadIdx.x] = 0;
    __syncthreads();
    for (int v = beg + threadIdx.x; v < end; v += blockDim.x)
        atomicAdd(&lh[min(degi[v], 255)], 1);
    __syncthreads();
    int c = lh[threadIdx.x];
    lb[threadIdx.x] = c ? atomicAdd(&dcur[threadIdx.x], c) : 0;
    __syncthreads();
    lh[threadIdx.x] = 0;
    __syncthreads();
    for (int v = beg + threadIdx.x; v < end; v += blockDim.x) {
        int bin = min(degi[v], 255);
        int r = atomicAdd(&lh[bin], 1);
        perm[lb[bin] + r] = v;
    }
}

// ---- x0s = bf16(dinv[v] * x) ----
__global__ void cvt_kernel(const float* __restrict__ x, const float* __restrict__ dinv,
                           unsigned short* __restrict__ xb, int n4) {
    int i = blockIdx.x * blockDim.x + threadIdx.x;
    if (i < n4) {
        float dv = dinv[i >> 4];
        float4 f = ((const float4*)x)[i];
        uint2 o;
        o.x = cvtpk(f.x * dv, f.y * dv);
        o.y = cvtpk(f.z * dv, f.w * dv);
        ((uint2*)xb)[i] = o;
    }
}

// ---- per-wave W A-fragments (W^T is the A operand) in REGISTERS, bf16 hi+lo.
// Lane l of wave wid holds A[m = l&15][k = (l>>4)*8 + j], j=0..7 for k-steps
// kk=0,1 -> W[kk*32 + (l>>4)*8 + j][wid*16 + (l&15)].
struct WFrag { short8 h0, l0, h1, l1; };
__device__ __forceinline__ WFrag load_wfrag(const float* __restrict__ W, int col, int kg) {
    union { short8 v; unsigned u[4]; } H0, L0, H1, L1;
#pragma unroll
    for (int j = 0; j < 4; ++j) {
        float w0 = W[(kg * 8 + 2 * j) * 64 + col];
        float w1 = W[(kg * 8 + 2 * j + 1) * 64 + col];
        unsigned h = cvtpk(w0, w1);
        float h0 = __uint_as_float(h << 16);
        float h1 = __uint_as_float(h & 0xffff0000u);
        H0.u[j] = h;
        L0.u[j] = cvtpk(w0 - h0, w1 - h1);
        float v0 = W[(32 + kg * 8 + 2 * j) * 64 + col];
        float v1 = W[(32 + kg * 8 + 2 * j + 1) * 64 + col];
        unsigned g = cvtpk(v0, v1);
        float g0 = __uint_as_float(g << 16);
        float g1 = __uint_as_float(g & 0xffff0000u);
        H1.u[j] = g;
        L1.u[j] = cvtpk(v0 - g0, v1 - g1);
    }
    WFrag r;
    r.h0 = H0.v; r.l0 = L0.v; r.h1 = H1.v; r.l1 = L1.v;
    return r;
}

// ---- build the B operand (t^T) fragment from an st row: 8 consecutive fp32,
// split into bf16 hi (RNE) + lo (RNE of exact residual) via v_cvt_pk_bf16_f32.
__device__ __forceinline__ void build_bfrag(const float* __restrict__ tp,
                                            short8* bh, short8* bl) {
    float4 ta = *(const float4*)tp;
    float4 tb = *(const float4*)(tp + 4);
    float tv[8] = {ta.x, ta.y, ta.z, ta.w, tb.x, tb.y, tb.z, tb.w};
    union { short8 v; unsigned u[4]; } H, L;
#pragma unroll
    for (int j = 0; j < 4; ++j) {
        unsigned h = cvtpk(tv[2 * j], tv[2 * j + 1]);
        float h0 = __uint_as_float(h << 16);
        float h1 = __uint_as_float(h & 0xffff0000u);
        H.u[j] = h;
        L.u[j] = cvtpk(tv[2 * j] - h0, tv[2 * j + 1] - h1);
    }
    *bh = H.v;
    *bl = L.v;
}

// 6-MFMA bf16x3 tile: hi*hi + lo*hi + hi*lo over 2 k-steps
__device__ __forceinline__ f32x4 mm6(const WFrag& w, short8 bh0, short8 bl0,
                                     short8 bh1, short8 bl1) {
    f32x4 ac = {0.f, 0.f, 0.f, 0.f};
    ac = MFMA16(w.h0, bh0, ac);
    ac = MFMA16(w.l0, bh0, ac);
    ac = MFMA16(w.h0, bl0, ac);
    ac = MFMA16(w.h1, bh1, ac);
    ac = MFMA16(w.l1, bh1, ac);
    ac = MFMA16(w.h1, bl1, ac);
    return ac;
}

// ---- 4-slot gather, 8-edge-deep pipeline: lane = (slot s = lane>>4, quad g = lane&15).
// All 8 srcid loads then all 8 row loads issued before the fma tree -> 8 fetches
// in flight per lane. No per-edge clamp: over-reads land in later CSR rows or the
// zeroed 64-entry pad and are masked out of the accumulation.
struct GRes { float a0, a1, a2, a3; };
__device__ __forceinline__ GRes gather8s(const int* __restrict__ srcids, int beg, int deg,
                                         int md, const unsigned short* __restrict__ xsb,
                                         int ge) {
    GRes r{0.0f, 0.0f, 0.0f, 0.0f};
    for (int i = 0; i < md; i += 8) {
        int src[8];
#pragma unroll
        for (int u = 0; u < 8; ++u)
            src[u] = srcids[beg + i + u];
        int2 q[8];
#pragma unroll
        for (int u = 0; u < 8; ++u)
            q[u] = *(const int2*)(xsb + ((unsigned)src[u] * 64u + (unsigned)ge));
#pragma unroll
        for (int u = 0; u < 8; ++u) {
            float m = (i + u < deg) ? 1.0f : 0.0f;
            r.a0 = fmaf(m, lo16(q[u].x), r.a0);
            r.a1 = fmaf(m, hi16(q[u].x), r.a1);
            r.a2 = fmaf(m, lo16(q[u].y), r.a2);
            r.a3 = fmaf(m, hi16(q[u].y), r.a3);
        }
    }
    return r;
}

// ---- fused GCN2Conv layer: ys_out = dinv * relu( t @ W ),
//      t = 0.9*dinv*(S + xs_self) + 0.1*sdeg*xs_self; block-coop MFMA (bf16x3).
// One tile per block. Epilogue bounces results through st so each 16-lane group
// writes one full 128B row contiguously (no partial-line RMW).
__global__ __launch_bounds__(256, 7) void layer_kernel(
        const int* __restrict__ rowptr, const int* __restrict__ degi,
        const int* __restrict__ srcids, const int* __restrict__ perm,
        const unsigned short* __restrict__ xsb, const float* __restrict__ dinv,
        const float* __restrict__ sdeg, const float* __restrict__ W,
        unsigned short* __restrict__ yb, int n) {
    __shared__ __align__(16) float st[16][68];             // 16 nodes x 64 feat (+4 pad)
    int wid = threadIdx.x >> 6;
    int lane = threadIdx.x & 63;
    int s = lane >> 4;    // gather: node slot   | matmul: k-group
    int g = lane & 15;    // gather: feature quad| matmul: node (B col / D col)
    WFrag wA = load_wfrag(W, wid * 16 + g, s);             // registers, once
    int ntile = (n + 15) >> 4;
    int tile = ntile - 1 - blockIdx.x;
    int base = tile * 16;
    int vb = base + wid * 4 + s;
    int vbc = (vb < n) ? vb : n - 1;
    int v = perm[vbc];
    int beg = rowptr[v];
    int deg = degi[v];
    int md = max(deg, __shfl_xor(deg, 16));
    md = max(md, __shfl_xor(md, 32));
    GRes r = gather8s(srcids, beg, deg, md, xsb, g * 4);
    int2 qs = *(const int2*)(xsb + ((unsigned)v * 64u + (unsigned)(g * 4)));
    float xs0 = lo16(qs.x), xs1 = hi16(qs.x), xs2 = lo16(qs.y), xs3 = hi16(qs.y);
    float c9 = 0.9f * dinv[v];
    float c1 = 0.1f * sdeg[v];
    float4 t4;
    t4.x = c9 * (r.a0 + xs0) + c1 * xs0;
    t4.y = c9 * (r.a1 + xs1) + c1 * xs1;
    t4.z = c9 * (r.a2 + xs2) + c1 * xs2;
    t4.w = c9 * (r.a3 + xs3) + c1 * xs3;
    *(float4*)&st[wid * 4 + s][g * 4] = t4;
    __syncthreads();                                   // (A) st tile complete
    // ---- MFMA: D[outf = wid*16 + s*4 + j][node = g] ----
    int vb2 = base + g;
    int v2c = perm[(vb2 < n) ? vb2 : n - 1];
    float dv2 = dinv[v2c];
    const float* strow = st[g];
    short8 bh0, bl0, bh1, bl1;
    build_bfrag(strow + s * 8,      &bh0, &bl0);
    build_bfrag(strow + 32 + s * 8, &bh1, &bl1);
    __syncthreads();                                   // (B) all st reads done
    f32x4 ac = mm6(wA, bh0, bl0, bh1, bl1);
    *(float4*)&st[g][wid * 16 + s * 4] = make_float4(
        fmaxf(ac[0], 0.f) * dv2, fmaxf(ac[1], 0.f) * dv2,
        fmaxf(ac[2], 0.f) * dv2, fmaxf(ac[3], 0.f) * dv2);
    __syncthreads();                                   // (C) results staged in st
    // coalesced full-row write: 16 lanes x 8B = 128B contiguous per node row
    int rowi = threadIdx.x >> 4;
    int quad = threadIdx.x & 15;
    int vbw = base + rowi;
    if (vbw < n) {
        int vw = perm[vbw];
        float4 y4 = *(const float4*)&st[rowi][quad * 4];
        uint2 o;
        o.x = cvtpk(y4.x, y4.y);
        o.y = cvtpk(y4.z, y4.w);
        *(uint2*)(yb + ((size_t)(unsigned)vw << 6) + (unsigned)(quad * 4)) = o;
    }
}

// ---- last GCN2Conv layer fused with GCNConv GEMM: xw = (dinv*relu(t@W)) @ Wg ----
__global__ __launch_bounds__(256, 6) void layer_fused_kernel(
        const int* __restrict__ rowptr, const int* __restrict__ degi,
        const int* __restrict__ srcids, const int* __restrict__ perm,
        const unsigned short* __restrict__ xsb, const float* __restrict__ dinv,
        const float* __restrict__ sdeg, const float* __restrict__ W,
        const float* __restrict__ Wg, unsigned short* __restrict__ yb, int n) {
    __shared__ __align__(16) float st[16][68];
    int wid = threadIdx.x >> 6;
    int lane = threadIdx.x & 63;
    int s = lane >> 4;
    int g = lane & 15;
    WFrag wA = load_wfrag(W,  wid * 16 + g, s);
    WFrag wG = load_wfrag(Wg, wid * 16 + g, s);
    int ntile = (n + 15) >> 4;
    int tile = ntile - 1 - blockIdx.x;
    int base = tile * 16;
    int vb = base + wid * 4 + s;
    int vbc = (vb < n) ? vb : n - 1;
    int v = perm[vbc];
    int beg = rowptr[v];
    int deg = degi[v];
    int md = max(deg, __shfl_xor(deg, 16));
    md = max(md, __shfl_xor(md, 32));
    GRes r = gather8s(srcids, beg, deg, md, xsb, g * 4);
    int2 qs = *(const int2*)(xsb + ((unsigned)v * 64u + (unsigned)(g * 4)));
    float xs0 = lo16(qs.x), xs1 = hi16(qs.x), xs2 = lo16(qs.y), xs3 = hi16(qs.y);
    float c9 = 0.9f * dinv[v];
    float c1 = 0.1f * sdeg[v];
    float4 t4;
    t4.x = c9 * (r.a0 + xs0) + c1 * xs0;
    t4.y = c9 * (r.a1 + xs1) + c1 * xs1;
    t4.z = c9 * (r.a2 + xs2) + c1 * xs2;
    t4.w = c9 * (r.a3 + xs3) + c1 * xs3;
    *(float4*)&st[wid * 4 + s][g * 4] = t4;
    __syncthreads();                                   // (A) st tile complete
    int vb2 = base + g;
    int v2c = perm[(vb2 < n) ? vb2 : n - 1];
    float dv2 = dinv[v2c];
    const float* strow = st[g];
    // ---- matmul 1: y3s = dinv * relu(t @ W), written back to st (fp32) ----
    {
        short8 bh0, bl0, bh1, bl1;
        build_bfrag(strow + s * 8,      &bh0, &bl0);
        build_bfrag(strow + 32 + s * 8, &bh1, &bl1);
        __syncthreads();                               // (B) all B1 reads done
        f32x4 ac = mm6(wA, bh0, bl0, bh1, bl1);
        *(float4*)&st[g][wid * 16 + s * 4] = make_float4(
            fmaxf(ac[0], 0.f) * dv2, fmaxf(ac[1], 0.f) * dv2,
            fmaxf(ac[2], 0.f) * dv2, fmaxf(ac[3], 0.f) * dv2);
    }
    __syncthreads();                                   // (C) y3s writeback complete
    // ---- matmul 2: xw = y3s @ Wg (no relu, no extra scale) ----
    {
        short8 bh0, bl0, bh1, bl1;
        build_bfrag(strow + s * 8,      &bh0, &bl0);
        build_bfrag(strow + 32 + s * 8, &bh1, &bl1);
        __syncthreads();                               // (D) B2 reads done
        f32x4 ac = mm6(wG, bh0, bl0, bh1, bl1);
        *(float4*)&st[g][wid * 16 + s * 4] = make_float4(ac[0], ac[1], ac[2], ac[3]);
    }
    __syncthreads();                                   // (E) xw staged in st
    // coalesced full-row write
    int rowi = threadIdx.x >> 4;
    int quad = threadIdx.x & 15;
    int vbw = base + rowi;
    if (vbw < n) {
        int vw = perm[vbw];
        float4 y4 = *(const float4*)&st[rowi][quad * 4];
        uint2 o;
        o.x = cvtpk(y4.x, y4.y);
        o.y = cvtpk(y4.z, y4.w);
        *(uint2*)(yb + ((size_t)(unsigned)vw << 6) + (unsigned)(quad * 4)) = o;
    }
}

// ---- final: h = dinv*(S + xws_self) + b_gcn; out1 = h@W1+b1; out2 = h@W2+b2 ----
__global__ __launch_bounds__(256, 7) void heads_kernel(
        const int* __restrict__ rowptr, const int* __restrict__ degi,
        const int* __restrict__ srcids, const int* __restrict__ perm,
        const unsigned short* __restrict__ xwb, const float* __restrict__ dinv,
        const float* __restrict__ bg,
        const float* __restrict__ W1, const float* __restrict__ b1,
        const float* __restrict__ W2, const float* __restrict__ b2,
        float* __restrict__ out, int n) {
    __shared__ __align__(16) float hs[4][4][64];
    __shared__ __align__(16) float whd[448];   // whd[j*64+k], j=0..6
    __shared__ float bs[8];
    int wid = threadIdx.x >> 6;
    int lane = threadIdx.x & 63;
    int s = lane >> 4;
    int g = lane & 15;
    for (int i = threadIdx.x; i < 448; i += TPB) {   // blockDim 256 < 448: loop!
        int j = i >> 6, k = i & 63;
        whd[i] = (j < 4) ? W1[k * 4 + j] : W2[k * 3 + (j - 4)];
    }
    if (threadIdx.x < 7) bs[threadIdx.x] = (threadIdx.x < 4) ? b1[threadIdx.x] : b2[threadIdx.x - 4];
    __syncthreads();
    int j = lane >> 3;
    int k0 = (lane & 7) * 8;
    int ntile = (n + 15) >> 4;
    int tile = ntile - 1 - blockIdx.x;
    int base = tile * 16 + wid * 4;
    int vb = base + s;
    int vbc = (vb < n) ? vb : n - 1;
    int v = perm[vbc];
    int beg = rowptr[v];
    int deg = degi[v];
    int md = max(deg, __shfl_xor(deg, 16));
    md = max(md, __shfl_xor(md, 32));
    GRes r = gather8s(srcids, beg, deg, md, xwb, g * 4);
    int2 qs = *(const int2*)(xwb + ((unsigned)v * 64u + (unsigned)(g * 4)));
    float dv = dinv[v];
    float4 bq = *(const float4*)(bg + g * 4);
    float4 h4;
    h4.x = dv * (r.a0 + lo16(qs.x)) + bq.x;
    h4.y = dv * (r.a1 + hi16(qs.x)) + bq.y;
    h4.z = dv * (r.a2 + lo16(qs.y)) + bq.z;
    h4.w = dv * (r.a3 + hi16(qs.y)) + bq.w;
    if (vb < n)
        *(float4*)&out[(size_t)7 * n + (size_t)(unsigned)v * 64 + g * 4] = h4;
    *(float4*)&hs[wid][s][g * 4] = h4;
    __builtin_amdgcn_wave_barrier();
#pragma unroll
    for (int ss = 0; ss < 4; ++ss) {
        int vb2 = base + ss;
        if (vb2 >= n) break;
        int v2 = perm[vb2];
        float part = 0.0f;
        if (j < 7) {
            float4 h0 = *(const float4*)&hs[wid][ss][k0];
            float4 h1 = *(const float4*)&hs[wid][ss][k0 + 4];
            const float4* wq = (const float4*)&whd[j * 64 + k0];
            float4 w0 = wq[0], w1 = wq[1];
            part = h0.x * w0.x + h0.y * w0.y + h0.z * w0.z + h0.w * w0.w
                 + h1.x * w1.x + h1.y * w1.y + h1.z * w1.z + h1.w * w1.w;
        }
        part += __shfl_down(part, 4);
        part += __shfl_down(part, 2);
        part += __shfl_down(part, 1);
        if ((lane & 7) == 0 && j < 7) {
            float sv = bs[j] + part;
            if (j < 4) out[(size_t)v2 * 4 + j] = sv;
            else       out[(size_t)4 * n + (size_t)v2 * 3 + (j - 4)] = sv;
        }
    }
}

extern "C" void kernel_launch(void* const* d_in, const int* in_sizes, int n_in,
                              void* d_out, int out_size, void* d_ws, size_t ws_size,
                              hipStream_t stream) {
    const float* x     = (const float*)d_in[0];
    const int*   ei    = (const int*)d_in[1];
    const float* Ws    = (const float*)d_in[2];
    const float* W_gcn = (const float*)d_in[3];
    const float* b_gcn = (const float*)d_in[4];
    const float* W1    = (const float*)d_in[5];
    const float* b1    = (const float*)d_in[6];
    const float* W2    = (const float*)d_in[7];
    const float* b2    = (const float*)d_in[8];
    float* out = (float*)d_out;

    const int N = in_sizes[0] / 64;
    const int E = in_sizes[1] / 2;
    const int NLAYERS = in_sizes[2] / 4096;  // L-1 = 3
    const int B = (N + 127) >> NBSH;         // node buckets of 128
    const int NTILE = (N + 15) >> 4;         // one block per 16-node tile

    // ws layout (ints): degi[N] rowptr[N] bh[800] bcur[800] boff[800]
    //                   dh[256] dcur[256] perm[N] srcids[E+64] ebuf[E]
    // (floats): dinv[N] sdeg[N] | (ushort): x0s, bufA, bufB (N*64 each)
    int*   degi   = (int*)d_ws;
    int*   rowptr = degi + N;
    int*   bh     = rowptr + N;
    int*   bcur   = bh + 800;
    int*   boff   = bcur + 800;
    int*   dh     = boff + 800;
    int*   dcur   = dh + 256;
    int*   perm   = dcur + 256;
    int*   srcids = perm + N;
    unsigned int* ebuf = (unsigned int*)(srcids + E + 64);
    float* dinv   = (float*)(ebuf + E);
    float* sdeg   = dinv + N;
    unsigned short* x0s  = (unsigned short*)(sdeg + N);
    unsigned short* bufA = x0s + (size_t)N * 64;
    unsigned short* bufB = bufA + (size_t)N * 64;

    // ---- CSR build: two-pass bucket sort ----
    hipMemsetAsync(bh, 0, 800 * sizeof(int), stream);
    hipMemsetAsync(dh, 0, 256 * sizeof(int), stream);
    hipMemsetAsync(srcids + E, 0, 64 * sizeof(int), stream);  // gather tail pad
    ebhist_kernel<<<120, TPB, 0, stream>>>(ei + E, bh, E, B);
    bscan_kernel<<<1, 256, 0, stream>>>(bh, bcur, boff, B, E);
    bucket_scatter_kernel<<<120, TPB, 0, stream>>>(ei, bcur, ebuf, E, B);
    bucket_place_kernel<<<B, 128, 0, stream>>>(boff, ebuf, rowptr, degi, dinv, sdeg,
                                               srcids, N);
    // ---- degree-sorted permutation ----
    dhist_kernel<<<64, 256, 0, stream>>>(degi, dh, N);
    dscan_kernel<<<1, 256, 0, stream>>>(dh, dcur);
    place_kernel<<<64, 256, 0, stream>>>(degi, dcur, perm, N);
    cvt_kernel<<<(N * 16 + TPB - 1) / TPB, TPB, 0, stream>>>(x, dinv, x0s, N * 16);

    // ---- GCN2Conv layers: first NLAYERS-1 plain, last fused with GCNConv GEMM ----
    const unsigned short* xcur = x0s;
    unsigned short* ybuf = bufA;
    for (int i = 0; i < NLAYERS - 1; ++i) {
        layer_kernel<<<NTILE, TPB, 0, stream>>>(rowptr, degi, srcids, perm, xcur,
                                                dinv, sdeg, Ws + (size_t)i * 4096, ybuf, N);
        xcur = ybuf;
        ybuf = (ybuf == bufA) ? bufB : bufA;
    }
    layer_fused_kernel<<<NTILE, TPB, 0, stream>>>(rowptr, degi, srcids, perm, xcur,
                                                  dinv, sdeg,
                                                  Ws + (size_t)(NLAYERS - 1) * 4096,
                                                  W_gcn, ybuf, N);
    unsigned short* xw = ybuf;

    // ---- heads ----
    heads_kernel<<<NTILE, TPB, 0, stream>>>(rowptr, degi, srcids, perm, xw, dinv,
                                            b_gcn, W1, b1, W2, b2, out, N);
}